// Round 7
// baseline (2670.896 us; speedup 1.0000x reference)
//
#include <hip/hip_runtime.h>
#include <hip/hip_bf16.h>
#include <stdint.h>

typedef _Float16 f16x8 __attribute__((ext_vector_type(8)));
typedef _Float16 f16x4 __attribute__((ext_vector_type(4)));
typedef float    f32x4 __attribute__((ext_vector_type(4)));

// ---------------------------------------------------------------------------
// global->LDS direct load, 16B per lane; LDS dest = wave-uniform base + lane*16
// ---------------------------------------------------------------------------
__device__ __forceinline__ void gload_lds16(const void* g, void* l) {
  __builtin_amdgcn_global_load_lds(
      reinterpret_cast<const __attribute__((address_space(1))) void*>(
          reinterpret_cast<uintptr_t>(g)),
      reinterpret_cast<__attribute__((address_space(3))) void*>(
          reinterpret_cast<uintptr_t>(l)),
      16, 0, 0);
}

// XOR swizzle within each 128B row, keyed off row&7 (bits 7-9 of byte offset).
__device__ __forceinline__ int swz(int o) { return o ^ ((o >> 3) & 0x70); }

// ---------------------------------------------------------------------------
// prepass 1: edge_rep = f16(relu(edge_ctx @ W_post_emb + b))  (1280x512x1024)
// ---------------------------------------------------------------------------
__global__ void k_edge(const float* __restrict__ ec, const float* __restrict__ W,
                       const float* __restrict__ b, _Float16* __restrict__ er)
{
  __shared__ float sec[8 * 512];
  const int t  = threadIdx.x;
  const int rb = blockIdx.x * 8;
#pragma unroll
  for (int j = 0; j < 16; ++j)
    sec[j * 256 + t] = ec[(size_t)rb * 512 + j * 256 + t];
  __syncthreads();

  const int c4 = t * 4;
  f32x4 acc[8];
#pragma unroll
  for (int r = 0; r < 8; ++r) acc[r] = f32x4{0.f, 0.f, 0.f, 0.f};

  for (int k = 0; k < 512; ++k) {
    f32x4 w = *reinterpret_cast<const f32x4*>(W + (size_t)k * 1024 + c4);
#pragma unroll
    for (int r = 0; r < 8; ++r) acc[r] += sec[r * 512 + k] * w;
  }
  f32x4 bb = *reinterpret_cast<const f32x4*>(b + c4);
#pragma unroll
  for (int r = 0; r < 8; ++r) {
    f32x4 o = acc[r] + bb;
    f16x4 h;
#pragma unroll
    for (int i = 0; i < 4; ++i) h[i] = (_Float16)(o[i] > 0.f ? o[i] : 0.f);
    *reinterpret_cast<f16x4*>(er + (size_t)(rb + r) * 1024 + c4) = h;
  }
}

// ---------------------------------------------------------------------------
// prepass 2: gather -> A_cat[r][c] = edge_rep[(c<512?p0:p1)][c]   (f16)
// ---------------------------------------------------------------------------
__global__ void k_gather(const _Float16* __restrict__ er, const int* __restrict__ pidx,
                         _Float16* __restrict__ Acat)
{
  const int r  = blockIdx.x;
  const int c4 = threadIdx.x * 4;
  const int obj = pidx[2 * r + (c4 >= 512 ? 1 : 0)];
  f16x4 v = *reinterpret_cast<const f16x4*>(er + (size_t)obj * 1024 + c4);
  *reinterpret_cast<f16x4*>(Acat + (size_t)r * 1024 + c4) = v;
}

// ---------------------------------------------------------------------------
// prepass 3: fp32 -> fp16 convert (union_features), 8 elems/thread
// ---------------------------------------------------------------------------
__global__ void k_cvt(const float* __restrict__ in, _Float16* __restrict__ out)
{
  const size_t g = (size_t)blockIdx.x * 256 + threadIdx.x;
  const f32x4* p = reinterpret_cast<const f32x4*>(in) + g * 2;
  f32x4 v0 = p[0], v1 = p[1];
  f16x8 h;
  h[0] = (_Float16)v0[0]; h[1] = (_Float16)v0[1];
  h[2] = (_Float16)v0[2]; h[3] = (_Float16)v0[3];
  h[4] = (_Float16)v1[0]; h[5] = (_Float16)v1[1];
  h[6] = (_Float16)v1[2]; h[7] = (_Float16)v1[3];
  *(reinterpret_cast<f16x8*>(out) + g) = h;
}

// ---------------------------------------------------------------------------
// prepass 4: Wt[n][k] = f16(W[k][n])  (tiled transpose via LDS)
// ---------------------------------------------------------------------------
__global__ void k_wt(const float* __restrict__ W, _Float16* __restrict__ Wt,
                     int K, int N)
{
  __shared__ float tile[64][65];
  const int ntn = N >> 6;
  const int kt = blockIdx.x / ntn, nt = blockIdx.x % ntn;
  const int tx = threadIdx.x & 63, ty = threadIdx.x >> 6;
  const int k0 = kt * 64, n0 = nt * 64;
#pragma unroll
  for (int j = 0; j < 16; ++j) {
    int kr = j * 4 + ty;
    tile[kr][tx] = W[(size_t)(k0 + kr) * N + n0 + tx];
  }
  __syncthreads();
#pragma unroll
  for (int j = 0; j < 16; ++j) {
    int nr = j * 4 + ty;
    Wt[(size_t)(n0 + nr) * K + k0 + tx] = (_Float16)tile[tx][nr];
  }
}

// ---------------------------------------------------------------------------
// staging: NI chunks of 8KB; linear LDS dest, source pre-swizzled. (r5-verified)
// ---------------------------------------------------------------------------
template<int NI>
__device__ __forceinline__ void stage_tile(const _Float16* __restrict__ src, int ldk,
                                           int rcBase, int kt, _Float16* sbuf, int tid)
{
#pragma unroll
  for (int j = 0; j < NI; ++j) {
    int o  = j * 8192 + tid * 16;          // linear LDS byte offset
    int op = swz(o);                        // logical (row,kbyte) it must hold
    int r  = op >> 7;
    int kh = (op & 127) >> 1;
    gload_lds16(src + (size_t)(rcBase + r) * ldk + kt + kh,
                sbuf + (o - (tid & 63) * 16) / 2);   // wave-uniform base
  }
}

// ---------------------------------------------------------------------------
// single-acc GEMM: C = A(MxK) @ Bt(NxK)^T + bias, 256x256 tile, BK=64,
// 512 thr = 8 waves (2x4), wave tile 128x64.
// REGISTER-PIPELINED 4-phase schedule: each phase issues the NEXT phase's
// ds_reads, then runs MFMA on fragments read one phase earlier -> DS pipe and
// MFMA pipe overlap. One {lgkmcnt+vmcnt+barrier} per K-tile, mid-tile.
// EPI=0: store f16 P.  EPI=1: out = (acc+bias) * P  (f32).
// ---------------------------------------------------------------------------
template<int KDIM, int EPI>
__global__ __launch_bounds__(512, 2) void k_gemm(
    const _Float16* __restrict__ A, const _Float16* __restrict__ Bt,
    const float* __restrict__ bias, const _Float16* __restrict__ P,
    float* __restrict__ out, _Float16* __restrict__ Pout)
{
  constexpr int NT = KDIM / 64;
  extern __shared__ char smem[];   // 2 dbuf x {A 32KB, B 32KB} = 128 KiB

  const int tid  = threadIdx.x;
  const int lane = tid & 63, lr = lane & 15, lg = lane >> 4;
  const int wid  = tid >> 6, wr = wid >> 2, wc = wid & 3;     // 2x4 wave grid

  // XCD-aware bijective swizzle over 4096 blocks (512/XCD), col-tile fastest
  const int bid = blockIdx.x;
  const int swb = (bid & 7) * 512 + (bid >> 3);
  const int rowBase = (swb >> 4) * 256;
  const int colBase = (swb & 15) * 256;

  const int key = (lr & 7) << 4;
  int kb[2];
  kb[0] = (lg * 16) ^ key;
  kb[1] = (64 + lg * 16) ^ key;
  const int aoff = (wr * 128 + lr) * 128;
  const int boff = (wc * 64 + lr) * 128;

  f16x8 af0[4][2], af1[4][2], bf0[2][2], bf1[2][2], bfn[2][2];
  f32x4 acc[8][4] = {};

  // ---- prologue: stage tiles 0 and 1; read tile 0's first fragments ----
  stage_tile<4>(A,  KDIM, rowBase, 0,  reinterpret_cast<_Float16*>(smem), tid);
  stage_tile<4>(Bt, KDIM, colBase, 0,  reinterpret_cast<_Float16*>(smem + 32768), tid);
  stage_tile<4>(A,  KDIM, rowBase, 64, reinterpret_cast<_Float16*>(smem + 65536), tid);
  stage_tile<4>(Bt, KDIM, colBase, 64, reinterpret_cast<_Float16*>(smem + 98304), tid);
  asm volatile("s_waitcnt vmcnt(8)" ::: "memory");   // tile 0 resident
  __builtin_amdgcn_s_barrier();
  {
    const char* aB = smem + aoff;
    const char* bB = smem + 32768 + boff;
#pragma unroll
    for (int m = 0; m < 4; ++m)
#pragma unroll
      for (int ks = 0; ks < 2; ++ks)
        af0[m][ks] = *reinterpret_cast<const f16x8*>(aB + m * 2048 + kb[ks]);
#pragma unroll
    for (int n = 0; n < 2; ++n)
#pragma unroll
      for (int ks = 0; ks < 2; ++ks)
        bf0[n][ks] = *reinterpret_cast<const f16x8*>(bB + n * 2048 + kb[ks]);
  }

  for (int t = 0; t < NT; ++t) {
    const char* aB = smem + (t & 1) * 65536 + aoff;            // cur A
    const char* bB = smem + (t & 1) * 65536 + 32768 + boff;    // cur B
    const char* aO = smem + ((t + 1) & 1) * 65536 + aoff;      // next A
    const char* bO = smem + ((t + 1) & 1) * 65536 + 32768 + boff;
    _Float16* stA = reinterpret_cast<_Float16*>(smem + (t & 1) * 65536);
    _Float16* stB = reinterpret_cast<_Float16*>(smem + (t & 1) * 65536 + 32768);

    // ---- P0: read bf1(t); MFMA af0·bf0 ----
#pragma unroll
    for (int n = 0; n < 2; ++n)
#pragma unroll
      for (int ks = 0; ks < 2; ++ks)
        bf1[n][ks] = *reinterpret_cast<const f16x8*>(bB + (2 + n) * 2048 + kb[ks]);
#pragma unroll
    for (int m = 0; m < 4; ++m)
#pragma unroll
      for (int n = 0; n < 2; ++n)
#pragma unroll
        for (int ks = 0; ks < 2; ++ks)
          acc[m][n] = __builtin_amdgcn_mfma_f32_16x16x32_f16(af0[m][ks], bf0[n][ks], acc[m][n], 0, 0, 0);

    // ---- P1: read af1(t); MFMA af0·bf1 ----
#pragma unroll
    for (int m = 0; m < 4; ++m)
#pragma unroll
      for (int ks = 0; ks < 2; ++ks)
        af1[m][ks] = *reinterpret_cast<const f16x8*>(aB + (4 + m) * 2048 + kb[ks]);
#pragma unroll
    for (int m = 0; m < 4; ++m)
#pragma unroll
      for (int n = 0; n < 2; ++n)
#pragma unroll
        for (int ks = 0; ks < 2; ++ks)
          acc[m][2 + n] = __builtin_amdgcn_mfma_f32_16x16x32_f16(af0[m][ks], bf1[n][ks], acc[m][2 + n], 0, 0, 0);

    // ---- boundary: all cur reads issued & drained; t+1 staged long ago ----
    asm volatile("s_waitcnt vmcnt(0) lgkmcnt(0)" ::: "memory");
    __builtin_amdgcn_s_barrier();
    if (t + 2 < NT) stage_tile<4>(A, KDIM, rowBase, (t + 2) * 64, stA, tid);

    // ---- P2: read af0(t+1) from other buf; MFMA af1·bf0 ----
    if (t + 1 < NT) {
#pragma unroll
      for (int m = 0; m < 4; ++m)
#pragma unroll
        for (int ks = 0; ks < 2; ++ks)
          af0[m][ks] = *reinterpret_cast<const f16x8*>(aO + m * 2048 + kb[ks]);
    }
#pragma unroll
    for (int m = 0; m < 4; ++m)
#pragma unroll
      for (int n = 0; n < 2; ++n)
#pragma unroll
        for (int ks = 0; ks < 2; ++ks)
          acc[4 + m][n] = __builtin_amdgcn_mfma_f32_16x16x32_f16(af1[m][ks], bf0[n][ks], acc[4 + m][n], 0, 0, 0);

    // ---- P3: stage B(t+2); read bf0'(t+1); MFMA af1·bf1 ----
    if (t + 2 < NT) stage_tile<4>(Bt, KDIM, colBase, (t + 2) * 64, stB, tid);
    if (t + 1 < NT) {
#pragma unroll
      for (int n = 0; n < 2; ++n)
#pragma unroll
        for (int ks = 0; ks < 2; ++ks)
          bfn[n][ks] = *reinterpret_cast<const f16x8*>(bO + n * 2048 + kb[ks]);
    }
#pragma unroll
    for (int m = 0; m < 4; ++m)
#pragma unroll
      for (int n = 0; n < 2; ++n)
#pragma unroll
        for (int ks = 0; ks < 2; ++ks)
          acc[4 + m][2 + n] = __builtin_amdgcn_mfma_f32_16x16x32_f16(af1[m][ks], bf1[n][ks], acc[4 + m][2 + n], 0, 0, 0);

    // rotate next-tile B fragments into bf0
#pragma unroll
    for (int n = 0; n < 2; ++n)
#pragma unroll
      for (int ks = 0; ks < 2; ++ks)
        bf0[n][ks] = bfn[n][ks];
  }

  // ---------------- epilogue ----------------
#pragma unroll
  for (int n = 0; n < 4; ++n) {
    const int col = colBase + wc * 64 + n * 16 + lr;
    const float bs = bias[col];
#pragma unroll
    for (int m = 0; m < 8; ++m) {
      const size_t row0 = rowBase + wr * 128 + m * 16 + lg * 4;
#pragma unroll
      for (int i = 0; i < 4; ++i) {
        const size_t idx = (row0 + i) * 4096 + col;
        if (EPI == 0) Pout[idx] = (_Float16)(acc[m][n][i] + bs);
        else          out[idx]  = (acc[m][n][i] + bs) * (float)P[idx];
      }
    }
  }
}

// ---------------------------------------------------------------------------
extern "C" void kernel_launch(void* const* d_in, const int* in_sizes, int n_in,
                              void* d_out, int out_size, void* d_ws, size_t ws_size,
                              hipStream_t stream)
{
  const float* edge_ctx = (const float*)d_in[0];
  const int*   pair_idx = (const int*)d_in[1];
  const float* uf       = (const float*)d_in[2];
  const float* Wpe      = (const float*)d_in[3];
  const float* bpe      = (const float*)d_in[4];
  const float* Wpc      = (const float*)d_in[5];
  const float* bpc      = (const float*)d_in[6];
  const float* Wup      = (const float*)d_in[7];
  const float* bup      = (const float*)d_in[8];
  float* out = (float*)d_out;

  char* ws = (char*)d_ws;
  size_t off = 0;
  _Float16* Pbuf = (_Float16*)(ws + off); off += 536870912;   // 512 MB
  _Float16* Acat = (_Float16*)(ws + off); off += 134217728;   // 128 MB
  _Float16* Auf  = (_Float16*)(ws + off); off += 268435456;   // 256 MB
  _Float16* Btc  = (_Float16*)(ws + off); off += 8388608;     //   8 MB
  _Float16* Btu  = (_Float16*)(ws + off); off += 16777216;    //  16 MB
  _Float16* edge_rep = (_Float16*)(ws + off);                 // 2.6 MB

  (void)hipFuncSetAttribute((const void*)(k_gemm<1024, 0>),
                            hipFuncAttributeMaxDynamicSharedMemorySize, 131072);
  (void)hipFuncSetAttribute((const void*)(k_gemm<2048, 1>),
                            hipFuncAttributeMaxDynamicSharedMemorySize, 131072);

  k_edge<<<160, 256, 0, stream>>>(edge_ctx, Wpe, bpe, edge_rep);
  k_wt<<<(1024 / 64) * (4096 / 64), 256, 0, stream>>>(Wpc, Btc, 1024, 4096);
  k_wt<<<(2048 / 64) * (4096 / 64), 256, 0, stream>>>(Wup, Btu, 2048, 4096);
  k_gather<<<65536, 256, 0, stream>>>(edge_rep, pair_idx, Acat);
  k_cvt<<<65536, 256, 0, stream>>>(uf, Auf);

  k_gemm<1024, 0><<<4096, 512, 131072, stream>>>(Acat, Btc, bpc, nullptr, nullptr, Pbuf);
  k_gemm<2048, 1><<<4096, 512, 131072, stream>>>(Auf, Btu, bup, Pbuf, out, nullptr);
}

// Round 8
// 2047.018 us; speedup vs baseline: 1.3048x; 1.3048x over previous
//
#include <hip/hip_runtime.h>
#include <hip/hip_bf16.h>
#include <stdint.h>

typedef _Float16 f16x8 __attribute__((ext_vector_type(8)));
typedef _Float16 f16x4 __attribute__((ext_vector_type(4)));
typedef float    f32x4 __attribute__((ext_vector_type(4)));

// ---------------------------------------------------------------------------
// global->LDS direct load, 16B per lane; LDS dest = wave-uniform base + lane*16
// ---------------------------------------------------------------------------
__device__ __forceinline__ void gload_lds16(const void* g, void* l) {
  __builtin_amdgcn_global_load_lds(
      reinterpret_cast<const __attribute__((address_space(1))) void*>(
          reinterpret_cast<uintptr_t>(g)),
      reinterpret_cast<__attribute__((address_space(3))) void*>(
          reinterpret_cast<uintptr_t>(l)),
      16, 0, 0);
}

// XOR swizzle within each 128B row, keyed off row&7 (bits 7-9 of byte offset).
__device__ __forceinline__ int swz(int o) { return o ^ ((o >> 3) & 0x70); }

// ---------------------------------------------------------------------------
// prepass 1: edge_rep = f16(relu(edge_ctx @ W_post_emb + b))  (1280x512x1024)
// ---------------------------------------------------------------------------
__global__ void k_edge(const float* __restrict__ ec, const float* __restrict__ W,
                       const float* __restrict__ b, _Float16* __restrict__ er)
{
  __shared__ float sec[8 * 512];
  const int t  = threadIdx.x;
  const int rb = blockIdx.x * 8;
#pragma unroll
  for (int j = 0; j < 16; ++j)
    sec[j * 256 + t] = ec[(size_t)rb * 512 + j * 256 + t];
  __syncthreads();

  const int c4 = t * 4;
  f32x4 acc[8];
#pragma unroll
  for (int r = 0; r < 8; ++r) acc[r] = f32x4{0.f, 0.f, 0.f, 0.f};

  for (int k = 0; k < 512; ++k) {
    f32x4 w = *reinterpret_cast<const f32x4*>(W + (size_t)k * 1024 + c4);
#pragma unroll
    for (int r = 0; r < 8; ++r) acc[r] += sec[r * 512 + k] * w;
  }
  f32x4 bb = *reinterpret_cast<const f32x4*>(b + c4);
#pragma unroll
  for (int r = 0; r < 8; ++r) {
    f32x4 o = acc[r] + bb;
    f16x4 h;
#pragma unroll
    for (int i = 0; i < 4; ++i) h[i] = (_Float16)(o[i] > 0.f ? o[i] : 0.f);
    *reinterpret_cast<f16x4*>(er + (size_t)(rb + r) * 1024 + c4) = h;
  }
}

// ---------------------------------------------------------------------------
// prepass 2: gather -> A_cat[r][c] = edge_rep[(c<512?p0:p1)][c]   (f16)
// ---------------------------------------------------------------------------
__global__ void k_gather(const _Float16* __restrict__ er, const int* __restrict__ pidx,
                         _Float16* __restrict__ Acat)
{
  const int r  = blockIdx.x;
  const int c4 = threadIdx.x * 4;
  const int obj = pidx[2 * r + (c4 >= 512 ? 1 : 0)];
  f16x4 v = *reinterpret_cast<const f16x4*>(er + (size_t)obj * 1024 + c4);
  *reinterpret_cast<f16x4*>(Acat + (size_t)r * 1024 + c4) = v;
}

// ---------------------------------------------------------------------------
// prepass 3: fp32 -> fp16 convert (union_features), 8 elems/thread
// ---------------------------------------------------------------------------
__global__ void k_cvt(const float* __restrict__ in, _Float16* __restrict__ out)
{
  const size_t g = (size_t)blockIdx.x * 256 + threadIdx.x;
  const f32x4* p = reinterpret_cast<const f32x4*>(in) + g * 2;
  f32x4 v0 = p[0], v1 = p[1];
  f16x8 h;
  h[0] = (_Float16)v0[0]; h[1] = (_Float16)v0[1];
  h[2] = (_Float16)v0[2]; h[3] = (_Float16)v0[3];
  h[4] = (_Float16)v1[0]; h[5] = (_Float16)v1[1];
  h[6] = (_Float16)v1[2]; h[7] = (_Float16)v1[3];
  *(reinterpret_cast<f16x8*>(out) + g) = h;
}

// ---------------------------------------------------------------------------
// prepass 4: Wt[n][k] = f16(W[k][n])  (tiled transpose via LDS)
// ---------------------------------------------------------------------------
__global__ void k_wt(const float* __restrict__ W, _Float16* __restrict__ Wt,
                     int K, int N)
{
  __shared__ float tile[64][65];
  const int ntn = N >> 6;
  const int kt = blockIdx.x / ntn, nt = blockIdx.x % ntn;
  const int tx = threadIdx.x & 63, ty = threadIdx.x >> 6;
  const int k0 = kt * 64, n0 = nt * 64;
#pragma unroll
  for (int j = 0; j < 16; ++j) {
    int kr = j * 4 + ty;
    tile[kr][tx] = W[(size_t)(k0 + kr) * N + n0 + tx];
  }
  __syncthreads();
#pragma unroll
  for (int j = 0; j < 16; ++j) {
    int nr = j * 4 + ty;
    Wt[(size_t)(n0 + nr) * K + k0 + tx] = (_Float16)tile[tx][nr];
  }
}

// ---------------------------------------------------------------------------
// staging: NI chunks of 8KB; linear LDS dest, source pre-swizzled. (verified)
// ---------------------------------------------------------------------------
template<int NI>
__device__ __forceinline__ void stage_tile(const _Float16* __restrict__ src, int ldk,
                                           int rcBase, int kt, _Float16* sbuf, int tid)
{
#pragma unroll
  for (int j = 0; j < NI; ++j) {
    int o  = j * 8192 + tid * 16;          // linear LDS byte offset
    int op = swz(o);                        // logical (row,kbyte) it must hold
    int r  = op >> 7;
    int kh = (op & 127) >> 1;
    gload_lds16(src + (size_t)(rcBase + r) * ldk + kt + kh,
                sbuf + (o - (tid & 63) * 16) / 2);   // wave-uniform base
  }
}

// ---------------------------------------------------------------------------
// main fused dual-GEMM: out = (Acat@Wc^T + bc) * (Auf@Wu^T + bu)
// BM=256 BN=128 BK=64, 512 thr = 8 waves (4x2), wave tile 64x64.
// r3 staging skeleton (3-buffer, depth-2, vmcnt(6), ONE barrier/tile) +
// counted-lgkmcnt cluster interleave: R1(8)+R2(4) -> lgkm(4) -> C1 ->
// R3(4) -> lgkm(4) -> C2 -> lgkm(0) -> C3+C4.
// Unified 48-tile K loop: tiles 0..31 = union (K=2048), 32..47 = cat (K=1024).
// ---------------------------------------------------------------------------
#define NT  48
#define NTU 32

__global__ __launch_bounds__(512, 2) void k_main(
    const _Float16* __restrict__ Acat, const _Float16* __restrict__ Auf,
    const _Float16* __restrict__ Btc,  const _Float16* __restrict__ Btu,
    const float* __restrict__ bcat, const float* __restrict__ bup,
    float* __restrict__ out)
{
  extern __shared__ char smem[];                    // 144 KiB dynamic
  _Float16* bufA[3] = { reinterpret_cast<_Float16*>(smem),
                        reinterpret_cast<_Float16*>(smem + 32768),
                        reinterpret_cast<_Float16*>(smem + 65536) };
  _Float16* bufB[3] = { reinterpret_cast<_Float16*>(smem + 98304),
                        reinterpret_cast<_Float16*>(smem + 98304 + 16384),
                        reinterpret_cast<_Float16*>(smem + 98304 + 32768) };

  const int tid  = threadIdx.x;
  const int lane = tid & 63, lr = lane & 15, lg = lane >> 4;
  const int wid  = tid >> 6, wr = wid >> 1, wc = wid & 1;      // 4x2 wave grid

  // XCD column-ownership mapping: xcd = bid&7 owns cols [xcd*512, xcd*512+512)
  // seq: colTile fastest (4 consecutive blocks share the A row-slice).
  const int bid = blockIdx.x;
  const int xcd = bid & 7;
  const int seq = bid >> 3;                 // 0..1023
  const int rowBase = (seq >> 2) * 256;     // 256 row groups
  const int colBase = (xcd * 4 + (seq & 3)) * 128;

  // per-thread swizzled LDS read offsets
  const int key  = (lr & 7) << 4;
  int kb[2];
  kb[0] = (lg * 16) ^ key;
  kb[1] = (64 + lg * 16) ^ key;
  const int aoff = (wr * 64 + lr) * 128;
  const int boff = (wc * 64 + lr) * 128;

  f16x8 af[2][2], ag[2][2], bf[4][2];
  f32x4 accU[4][4] = {};
  f32x4 accP[4][4] = {};

  // rotating buffer pointers: cur = tile t, nxt = t+1, fre = stage target (t+2)
  _Float16 *Ac = bufA[0], *An = bufA[1], *Af = bufA[2];
  _Float16 *Bc = bufB[0], *Bn = bufB[1], *Bf = bufB[2];

  // prologue: stage tiles 0 and 1
  stage_tile<4>(Auf, 2048, rowBase, 0,  Ac, tid);
  stage_tile<2>(Btu, 2048, colBase, 0,  Bc, tid);
  stage_tile<4>(Auf, 2048, rowBase, 64, An, tid);
  stage_tile<2>(Btu, 2048, colBase, 64, Bn, tid);

#define TILE_BODY(ACC)                                                          \
  do {                                                                          \
    if (t < NT - 1) asm volatile("s_waitcnt vmcnt(6)" ::: "memory");            \
    else            asm volatile("s_waitcnt vmcnt(0)" ::: "memory");            \
    __builtin_amdgcn_s_barrier();                                               \
    __builtin_amdgcn_sched_barrier(0);                                          \
    if (t + 2 < NT) {                                                           \
      const int tt = t + 2;                                                     \
      if (tt < NTU) { stage_tile<4>(Auf,  2048, rowBase, tt * 64, Af, tid);     \
                      stage_tile<2>(Btu,  2048, colBase, tt * 64, Bf, tid); }   \
      else          { stage_tile<4>(Acat, 1024, rowBase, (tt - NTU) * 64, Af, tid); \
                      stage_tile<2>(Btc,  1024, colBase, (tt - NTU) * 64, Bf, tid); } \
    }                                                                           \
    const char* aB = reinterpret_cast<const char*>(Ac) + aoff;                  \
    const char* bB = reinterpret_cast<const char*>(Bc) + boff;                  \
    /* R1: af m0,m1 + bf n0,n1 (8 reads) ; R2: bf n2,n3 (4 reads) */            \
    _Pragma("unroll") for (int m = 0; m < 2; ++m)                               \
      _Pragma("unroll") for (int ks = 0; ks < 2; ++ks)                          \
        af[m][ks] = *reinterpret_cast<const f16x8*>(aB + m * 2048 + kb[ks]);    \
    _Pragma("unroll") for (int n = 0; n < 4; ++n)                               \
      _Pragma("unroll") for (int ks = 0; ks < 2; ++ks)                          \
        bf[n][ks] = *reinterpret_cast<const f16x8*>(bB + n * 2048 + kb[ks]);    \
    __builtin_amdgcn_sched_barrier(0);                                          \
    asm volatile("s_waitcnt lgkmcnt(4)" ::: "memory");                          \
    __builtin_amdgcn_sched_barrier(0);                                          \
    __builtin_amdgcn_s_setprio(1);                                              \
    _Pragma("unroll") for (int m = 0; m < 2; ++m)                               \
      _Pragma("unroll") for (int n = 0; n < 2; ++n)                             \
        _Pragma("unroll") for (int ks = 0; ks < 2; ++ks)                        \
          ACC[m][n] = __builtin_amdgcn_mfma_f32_16x16x32_f16(af[m][ks], bf[n][ks], ACC[m][n], 0, 0, 0); \
    __builtin_amdgcn_s_setprio(0);                                              \
    __builtin_amdgcn_sched_barrier(0);                                          \
    /* R3: af m2,m3 (4 reads) */                                                \
    _Pragma("unroll") for (int m = 0; m < 2; ++m)                               \
      _Pragma("unroll") for (int ks = 0; ks < 2; ++ks)                          \
        ag[m][ks] = *reinterpret_cast<const f16x8*>(aB + (2 + m) * 2048 + kb[ks]); \
    __builtin_amdgcn_sched_barrier(0);                                          \
    asm volatile("s_waitcnt lgkmcnt(4)" ::: "memory");                          \
    __builtin_amdgcn_sched_barrier(0);                                          \
    __builtin_amdgcn_s_setprio(1);                                              \
    _Pragma("unroll") for (int m = 0; m < 2; ++m)                               \
      _Pragma("unroll") for (int n = 0; n < 2; ++n)                             \
        _Pragma("unroll") for (int ks = 0; ks < 2; ++ks)                        \
          ACC[m][2 + n] = __builtin_amdgcn_mfma_f32_16x16x32_f16(af[m][ks], bf[2 + n][ks], ACC[m][2 + n], 0, 0, 0); \
    __builtin_amdgcn_s_setprio(0);                                              \
    asm volatile("s_waitcnt lgkmcnt(0)" ::: "memory");                          \
    __builtin_amdgcn_sched_barrier(0);                                          \
    __builtin_amdgcn_s_setprio(1);                                              \
    _Pragma("unroll") for (int m = 0; m < 2; ++m)                               \
      _Pragma("unroll") for (int n = 0; n < 2; ++n)                             \
        _Pragma("unroll") for (int ks = 0; ks < 2; ++ks)                        \
          ACC[2 + m][n] = __builtin_amdgcn_mfma_f32_16x16x32_f16(ag[m][ks], bf[n][ks], ACC[2 + m][n], 0, 0, 0); \
    _Pragma("unroll") for (int m = 0; m < 2; ++m)                               \
      _Pragma("unroll") for (int n = 0; n < 2; ++n)                             \
        _Pragma("unroll") for (int ks = 0; ks < 2; ++ks)                        \
          ACC[2 + m][2 + n] = __builtin_amdgcn_mfma_f32_16x16x32_f16(ag[m][ks], bf[2 + n][ks], ACC[2 + m][2 + n], 0, 0, 0); \
    __builtin_amdgcn_s_setprio(0);                                              \
    __builtin_amdgcn_sched_barrier(0);                                          \
    _Float16* tA = Ac; Ac = An; An = Af; Af = tA;                               \
    _Float16* tB = Bc; Bc = Bn; Bn = Bf; Bf = tB;                               \
  } while (0)

  for (int t = 0; t < NTU; ++t) TILE_BODY(accU);
  for (int t = NTU; t < NT; ++t) TILE_BODY(accP);
#undef TILE_BODY

  // ---------------- epilogue ----------------
#pragma unroll
  for (int n = 0; n < 4; ++n) {
    const int col = colBase + wc * 64 + n * 16 + lr;
    const float bc = bcat[col], bu = bup[col];
#pragma unroll
    for (int m = 0; m < 4; ++m) {
      const int row0 = rowBase + wr * 64 + m * 16 + lg * 4;
#pragma unroll
      for (int i = 0; i < 4; ++i)
        out[(size_t)(row0 + i) * 4096 + col] =
            (accP[m][n][i] + bc) * (accU[m][n][i] + bu);
    }
  }
}

// ---------------------------------------------------------------------------
extern "C" void kernel_launch(void* const* d_in, const int* in_sizes, int n_in,
                              void* d_out, int out_size, void* d_ws, size_t ws_size,
                              hipStream_t stream)
{
  const float* edge_ctx = (const float*)d_in[0];
  const int*   pair_idx = (const int*)d_in[1];
  const float* uf       = (const float*)d_in[2];
  const float* Wpe      = (const float*)d_in[3];
  const float* bpe      = (const float*)d_in[4];
  const float* Wpc      = (const float*)d_in[5];
  const float* bpc      = (const float*)d_in[6];
  const float* Wup      = (const float*)d_in[7];
  const float* bup      = (const float*)d_in[8];
  float* out = (float*)d_out;

  char* ws = (char*)d_ws;
  _Float16* edge_rep = (_Float16*)ws;                                // 2.6 MB region
  _Float16* Acat = (_Float16*)(ws + 5242880);                        // 128 MB
  _Float16* Auf  = (_Float16*)(ws + 5242880 + 134217728);            // 256 MB
  _Float16* Btc  = (_Float16*)(ws + 5242880 + 134217728 + 268435456);           // 8 MB
  _Float16* Btu  = (_Float16*)(ws + 5242880 + 134217728 + 268435456 + 8388608); // 16 MB

  (void)hipFuncSetAttribute((const void*)k_main,
                            hipFuncAttributeMaxDynamicSharedMemorySize, 147456);

  k_edge<<<160, 256, 0, stream>>>(edge_ctx, Wpe, bpe, edge_rep);
  k_wt<<<(1024 / 64) * (4096 / 64), 256, 0, stream>>>(Wpc, Btc, 1024, 4096);
  k_wt<<<(2048 / 64) * (4096 / 64), 256, 0, stream>>>(Wup, Btu, 2048, 4096);
  k_gather<<<65536, 256, 0, stream>>>(edge_rep, pair_idx, Acat);
  k_cvt<<<65536, 256, 0, stream>>>(uf, Auf);
  k_main<<<8192, 512, 147456, stream>>>(Acat, Auf, Btc, Btu, bpc, bup, out);
}

// Round 9
// 2035.494 us; speedup vs baseline: 1.3122x; 1.0057x over previous
//
#include <hip/hip_runtime.h>
#include <hip/hip_bf16.h>
#include <stdint.h>

typedef _Float16 f16x8 __attribute__((ext_vector_type(8)));
typedef _Float16 f16x4 __attribute__((ext_vector_type(4)));
typedef float    f32x4 __attribute__((ext_vector_type(4)));

// ---------------------------------------------------------------------------
// global->LDS direct load, 16B per lane; LDS dest = wave-uniform base + lane*16
// ---------------------------------------------------------------------------
__device__ __forceinline__ void gload_lds16(const void* g, void* l) {
  __builtin_amdgcn_global_load_lds(
      reinterpret_cast<const __attribute__((address_space(1))) void*>(
          reinterpret_cast<uintptr_t>(g)),
      reinterpret_cast<__attribute__((address_space(3))) void*>(
          reinterpret_cast<uintptr_t>(l)),
      16, 0, 0);
}

// XOR swizzle within each 128B row, keyed off row&7 (bits 7-9 of byte offset).
__device__ __forceinline__ int swz(int o) { return o ^ ((o >> 3) & 0x70); }

// ---------------------------------------------------------------------------
// prepass 1: edge_rep = f16(relu(edge_ctx @ W_post_emb + b))  (1280x512x1024)
// ---------------------------------------------------------------------------
__global__ void k_edge(const float* __restrict__ ec, const float* __restrict__ W,
                       const float* __restrict__ b, _Float16* __restrict__ er)
{
  __shared__ float sec[8 * 512];
  const int t  = threadIdx.x;
  const int rb = blockIdx.x * 8;
#pragma unroll
  for (int j = 0; j < 16; ++j)
    sec[j * 256 + t] = ec[(size_t)rb * 512 + j * 256 + t];
  __syncthreads();

  const int c4 = t * 4;
  f32x4 acc[8];
#pragma unroll
  for (int r = 0; r < 8; ++r) acc[r] = f32x4{0.f, 0.f, 0.f, 0.f};

  for (int k = 0; k < 512; ++k) {
    f32x4 w = *reinterpret_cast<const f32x4*>(W + (size_t)k * 1024 + c4);
#pragma unroll
    for (int r = 0; r < 8; ++r) acc[r] += sec[r * 512 + k] * w;
  }
  f32x4 bb = *reinterpret_cast<const f32x4*>(b + c4);
#pragma unroll
  for (int r = 0; r < 8; ++r) {
    f32x4 o = acc[r] + bb;
    f16x4 h;
#pragma unroll
    for (int i = 0; i < 4; ++i) h[i] = (_Float16)(o[i] > 0.f ? o[i] : 0.f);
    *reinterpret_cast<f16x4*>(er + (size_t)(rb + r) * 1024 + c4) = h;
  }
}

// ---------------------------------------------------------------------------
// prepass 2: gather -> A_cat[r][c] = edge_rep[(c<512?p0:p1)][c]   (f16)
// ---------------------------------------------------------------------------
__global__ void k_gather(const _Float16* __restrict__ er, const int* __restrict__ pidx,
                         _Float16* __restrict__ Acat)
{
  const int r  = blockIdx.x;
  const int c4 = threadIdx.x * 4;
  const int obj = pidx[2 * r + (c4 >= 512 ? 1 : 0)];
  f16x4 v = *reinterpret_cast<const f16x4*>(er + (size_t)obj * 1024 + c4);
  *reinterpret_cast<f16x4*>(Acat + (size_t)r * 1024 + c4) = v;
}

// ---------------------------------------------------------------------------
// prepass 3: fp32 -> fp16 convert (union_features), 8 elems/thread
// ---------------------------------------------------------------------------
__global__ void k_cvt(const float* __restrict__ in, _Float16* __restrict__ out)
{
  const size_t g = (size_t)blockIdx.x * 256 + threadIdx.x;
  const f32x4* p = reinterpret_cast<const f32x4*>(in) + g * 2;
  f32x4 v0 = p[0], v1 = p[1];
  f16x8 h;
  h[0] = (_Float16)v0[0]; h[1] = (_Float16)v0[1];
  h[2] = (_Float16)v0[2]; h[3] = (_Float16)v0[3];
  h[4] = (_Float16)v1[0]; h[5] = (_Float16)v1[1];
  h[6] = (_Float16)v1[2]; h[7] = (_Float16)v1[3];
  *(reinterpret_cast<f16x8*>(out) + g) = h;
}

// ---------------------------------------------------------------------------
// prepass 4: Wt[n][k] = f16(W[k][n])  (tiled transpose via LDS)
// ---------------------------------------------------------------------------
__global__ void k_wt(const float* __restrict__ W, _Float16* __restrict__ Wt,
                     int K, int N)
{
  __shared__ float tile[64][65];
  const int ntn = N >> 6;
  const int kt = blockIdx.x / ntn, nt = blockIdx.x % ntn;
  const int tx = threadIdx.x & 63, ty = threadIdx.x >> 6;
  const int k0 = kt * 64, n0 = nt * 64;
#pragma unroll
  for (int j = 0; j < 16; ++j) {
    int kr = j * 4 + ty;
    tile[kr][tx] = W[(size_t)(k0 + kr) * N + n0 + tx];
  }
  __syncthreads();
#pragma unroll
  for (int j = 0; j < 16; ++j) {
    int nr = j * 4 + ty;
    Wt[(size_t)(n0 + nr) * K + k0 + tx] = (_Float16)tile[tx][nr];
  }
}

// ---------------------------------------------------------------------------
// staging: NI chunks of 8KB; linear LDS dest, source pre-swizzled. (verified)
// ---------------------------------------------------------------------------
template<int NI>
__device__ __forceinline__ void stage_tile(const _Float16* __restrict__ src, int ldk,
                                           int rcBase, int kt, _Float16* sbuf, int tid)
{
#pragma unroll
  for (int j = 0; j < NI; ++j) {
    int o  = j * 8192 + tid * 16;          // linear LDS byte offset
    int op = swz(o);                        // logical (row,kbyte) it must hold
    int r  = op >> 7;
    int kh = (op & 127) >> 1;
    gload_lds16(src + (size_t)(rcBase + r) * ldk + kt + kh,
                sbuf + (o - (tid & 63) * 16) / 2);   // wave-uniform base
  }
}

// ---------------------------------------------------------------------------
// main fused dual-GEMM: out = (Acat@Wc^T + bc) * (Auf@Wu^T + bu)
// BM=256 BN=128 BK=64, 512 thr = 8 waves (4x2), wave tile 64x64.
// r8 skeleton (3-buffer, depth-2, vmcnt(6), ONE barrier/tile, XCD-col map)
// with an UNFENCED tile interior: 16 ds_read_b128 + 32 MFMA in one region,
// compiler-scheduled (fine-grained counted lgkmcnt, VALU hidden under MFMA).
// Unified 48-tile K loop: tiles 0..31 = union (K=2048), 32..47 = cat (K=1024).
// ---------------------------------------------------------------------------
#define NT  48
#define NTU 32

__global__ __launch_bounds__(512, 2) void k_main(
    const _Float16* __restrict__ Acat, const _Float16* __restrict__ Auf,
    const _Float16* __restrict__ Btc,  const _Float16* __restrict__ Btu,
    const float* __restrict__ bcat, const float* __restrict__ bup,
    float* __restrict__ out)
{
  extern __shared__ char smem[];                    // 144 KiB dynamic
  _Float16* bufA[3] = { reinterpret_cast<_Float16*>(smem),
                        reinterpret_cast<_Float16*>(smem + 32768),
                        reinterpret_cast<_Float16*>(smem + 65536) };
  _Float16* bufB[3] = { reinterpret_cast<_Float16*>(smem + 98304),
                        reinterpret_cast<_Float16*>(smem + 98304 + 16384),
                        reinterpret_cast<_Float16*>(smem + 98304 + 32768) };

  const int tid  = threadIdx.x;
  const int lane = tid & 63, lr = lane & 15, lg = lane >> 4;
  const int wid  = tid >> 6, wr = wid >> 1, wc = wid & 1;      // 4x2 wave grid

  // XCD column-ownership mapping: xcd = bid&7 owns cols [xcd*512, xcd*512+512)
  const int bid = blockIdx.x;
  const int xcd = bid & 7;
  const int seq = bid >> 3;                 // 0..1023
  const int rowBase = (seq >> 2) * 256;
  const int colBase = (xcd * 4 + (seq & 3)) * 128;

  // per-thread swizzled LDS read offsets
  const int key  = (lr & 7) << 4;
  int kb[2];
  kb[0] = (lg * 16) ^ key;
  kb[1] = (64 + lg * 16) ^ key;
  const int aoff = (wr * 64 + lr) * 128;
  const int boff = (wc * 64 + lr) * 128;

  f16x8 af[4][2], bf[4][2];
  f32x4 accU[4][4] = {};
  f32x4 accP[4][4] = {};

  // rotating buffer pointers: cur = tile t, nxt = t+1, fre = stage target (t+2)
  _Float16 *Ac = bufA[0], *An = bufA[1], *Af = bufA[2];
  _Float16 *Bc = bufB[0], *Bn = bufB[1], *Bf = bufB[2];

  // prologue: stage tiles 0 and 1
  stage_tile<4>(Auf, 2048, rowBase, 0,  Ac, tid);
  stage_tile<2>(Btu, 2048, colBase, 0,  Bc, tid);
  stage_tile<4>(Auf, 2048, rowBase, 64, An, tid);
  stage_tile<2>(Btu, 2048, colBase, 64, Bn, tid);

#define TILE_BODY(ACC)                                                          \
  do {                                                                          \
    if (t < NT - 1) asm volatile("s_waitcnt vmcnt(6)" ::: "memory");            \
    else            asm volatile("s_waitcnt vmcnt(0)" ::: "memory");            \
    __builtin_amdgcn_s_barrier();                                               \
    if (t + 2 < NT) {                                                           \
      const int tt = t + 2;                                                     \
      if (tt < NTU) { stage_tile<4>(Auf,  2048, rowBase, tt * 64, Af, tid);     \
                      stage_tile<2>(Btu,  2048, colBase, tt * 64, Bf, tid); }   \
      else          { stage_tile<4>(Acat, 1024, rowBase, (tt - NTU) * 64, Af, tid); \
                      stage_tile<2>(Btc,  1024, colBase, (tt - NTU) * 64, Bf, tid); } \
    }                                                                           \
    const char* aB = reinterpret_cast<const char*>(Ac) + aoff;                  \
    const char* bB = reinterpret_cast<const char*>(Bc) + boff;                  \
    /* unfenced: compiler interleaves read issue, addr VALU and MFMA */         \
    _Pragma("unroll") for (int m = 0; m < 4; ++m)                               \
      _Pragma("unroll") for (int ks = 0; ks < 2; ++ks)                          \
        af[m][ks] = *reinterpret_cast<const f16x8*>(aB + m * 2048 + kb[ks]);    \
    _Pragma("unroll") for (int n = 0; n < 4; ++n)                               \
      _Pragma("unroll") for (int ks = 0; ks < 2; ++ks)                          \
        bf[n][ks] = *reinterpret_cast<const f16x8*>(bB + n * 2048 + kb[ks]);    \
    _Pragma("unroll") for (int m = 0; m < 4; ++m)                               \
      _Pragma("unroll") for (int n = 0; n < 4; ++n)                             \
        _Pragma("unroll") for (int ks = 0; ks < 2; ++ks)                        \
          ACC[m][n] = __builtin_amdgcn_mfma_f32_16x16x32_f16(af[m][ks], bf[n][ks], ACC[m][n], 0, 0, 0); \
    _Float16* tA = Ac; Ac = An; An = Af; Af = tA;                               \
    _Float16* tB = Bc; Bc = Bn; Bn = Bf; Bf = tB;                               \
  } while (0)

  for (int t = 0; t < NTU; ++t) TILE_BODY(accU);
  for (int t = NTU; t < NT; ++t) TILE_BODY(accP);
#undef TILE_BODY

  // ---------------- epilogue ----------------
#pragma unroll
  for (int n = 0; n < 4; ++n) {
    const int col = colBase + wc * 64 + n * 16 + lr;
    const float bc = bcat[col], bu = bup[col];
#pragma unroll
    for (int m = 0; m < 4; ++m) {
      const int row0 = rowBase + wr * 64 + m * 16 + lg * 4;
#pragma unroll
      for (int i = 0; i < 4; ++i)
        out[(size_t)(row0 + i) * 4096 + col] =
            (accP[m][n][i] + bc) * (accU[m][n][i] + bu);
    }
  }
}

// ---------------------------------------------------------------------------
extern "C" void kernel_launch(void* const* d_in, const int* in_sizes, int n_in,
                              void* d_out, int out_size, void* d_ws, size_t ws_size,
                              hipStream_t stream)
{
  const float* edge_ctx = (const float*)d_in[0];
  const int*   pair_idx = (const int*)d_in[1];
  const float* uf       = (const float*)d_in[2];
  const float* Wpe      = (const float*)d_in[3];
  const float* bpe      = (const float*)d_in[4];
  const float* Wpc      = (const float*)d_in[5];
  const float* bpc      = (const float*)d_in[6];
  const float* Wup      = (const float*)d_in[7];
  const float* bup      = (const float*)d_in[8];
  float* out = (float*)d_out;

  char* ws = (char*)d_ws;
  _Float16* edge_rep = (_Float16*)ws;                                // 2.6 MB region
  _Float16* Acat = (_Float16*)(ws + 5242880);                        // 128 MB
  _Float16* Auf  = (_Float16*)(ws + 5242880 + 134217728);            // 256 MB
  _Float16* Btc  = (_Float16*)(ws + 5242880 + 134217728 + 268435456);           // 8 MB
  _Float16* Btu  = (_Float16*)(ws + 5242880 + 134217728 + 268435456 + 8388608); // 16 MB

  (void)hipFuncSetAttribute((const void*)k_main,
                            hipFuncAttributeMaxDynamicSharedMemorySize, 147456);

  k_edge<<<160, 256, 0, stream>>>(edge_ctx, Wpe, bpe, edge_rep);
  k_wt<<<(1024 / 64) * (4096 / 64), 256, 0, stream>>>(Wpc, Btc, 1024, 4096);
  k_wt<<<(2048 / 64) * (4096 / 64), 256, 0, stream>>>(Wup, Btu, 2048, 4096);
  k_gather<<<65536, 256, 0, stream>>>(edge_rep, pair_idx, Acat);
  k_cvt<<<65536, 256, 0, stream>>>(uf, Auf);
  k_main<<<8192, 512, 147456, stream>>>(Acat, Auf, Btc, Btu, bpc, bup, out);
}

// Round 10
// 1987.509 us; speedup vs baseline: 1.3438x; 1.0241x over previous
//
#include <hip/hip_runtime.h>
#include <hip/hip_bf16.h>
#include <stdint.h>

typedef _Float16 f16x8 __attribute__((ext_vector_type(8)));
typedef _Float16 f16x4 __attribute__((ext_vector_type(4)));
typedef float    f32x4 __attribute__((ext_vector_type(4)));

// ---------------------------------------------------------------------------
// global->LDS direct load, 16B per lane; LDS dest = wave-uniform base + lane*16
// ---------------------------------------------------------------------------
__device__ __forceinline__ void gload_lds16(const void* g, void* l) {
  __builtin_amdgcn_global_load_lds(
      reinterpret_cast<const __attribute__((address_space(1))) void*>(
          reinterpret_cast<uintptr_t>(g)),
      reinterpret_cast<__attribute__((address_space(3))) void*>(
          reinterpret_cast<uintptr_t>(l)),
      16, 0, 0);
}

// XOR swizzle within each 128B row, keyed off row&7 (bits 7-9 of byte offset).
__device__ __forceinline__ int swz(int o) { return o ^ ((o >> 3) & 0x70); }

// ---------------------------------------------------------------------------
// merged prepass kernel, role-split by blockIdx:
//   [0, 65536)          : cvt union_features f32 -> f16      (bulk stream)
//   [65536, 66560)      : transpose Wpc  (1024x4096 -> Btc)
//   [66560, 68608)      : transpose Wup  (2048x4096 -> Btu)
//   [68608, 68768)      : edge_rep = f16(relu(edge_ctx @ Wpe + bpe))
// ---------------------------------------------------------------------------
__global__ __launch_bounds__(256) void k_pre(
    const float* __restrict__ uf,  _Float16* __restrict__ Auf,
    const float* __restrict__ Wpc, _Float16* __restrict__ Btc,
    const float* __restrict__ Wup, _Float16* __restrict__ Btu,
    const float* __restrict__ ec,  const float* __restrict__ Wpe,
    const float* __restrict__ bpe, _Float16* __restrict__ er)
{
  __shared__ float lds_f[64 * 65];   // wt tile / edge sec (16.6KB)
  const int b = blockIdx.x;
  const int t = threadIdx.x;

  if (b < 65536) {
    // ---- cvt: 8 f32 -> 8 f16 per thread ----
    const size_t g = (size_t)b * 256 + t;
    const f32x4* p = reinterpret_cast<const f32x4*>(uf) + g * 2;
    f32x4 v0 = p[0], v1 = p[1];
    f16x8 h;
    h[0] = (_Float16)v0[0]; h[1] = (_Float16)v0[1];
    h[2] = (_Float16)v0[2]; h[3] = (_Float16)v0[3];
    h[4] = (_Float16)v1[0]; h[5] = (_Float16)v1[1];
    h[6] = (_Float16)v1[2]; h[7] = (_Float16)v1[3];
    *(reinterpret_cast<f16x8*>(Auf) + g) = h;
    return;
  }

  if (b < 68608) {
    // ---- weight transpose: Wt[n][k] = f16(W[k][n]) ----
    const float* W; _Float16* Wt; int K, bid2;
    if (b < 66560) { W = Wpc; Wt = Btc; K = 1024; bid2 = b - 65536; }
    else           { W = Wup; Wt = Btu; K = 2048; bid2 = b - 66560; }
    const int ntn = 4096 >> 6;
    const int kt = bid2 / ntn, nt = bid2 % ntn;
    const int tx = t & 63, ty = t >> 6;
    const int k0 = kt * 64, n0 = nt * 64;
#pragma unroll
    for (int j = 0; j < 16; ++j) {
      int kr = j * 4 + ty;
      lds_f[kr * 65 + tx] = W[(size_t)(k0 + kr) * 4096 + n0 + tx];
    }
    __syncthreads();
#pragma unroll
    for (int j = 0; j < 16; ++j) {
      int nr = j * 4 + ty;
      Wt[(size_t)(n0 + nr) * K + k0 + tx] = (_Float16)lds_f[tx * 65 + nr];
    }
    return;
  }

  // ---- edge: 8 rows per block, fp32 accumulate, relu, f16 store ----
  {
    const int rb = (b - 68608) * 8;
    float* sec = lds_f;   // 8*512 floats = 16KB
#pragma unroll
    for (int j = 0; j < 16; ++j)
      sec[j * 256 + t] = ec[(size_t)rb * 512 + j * 256 + t];
    __syncthreads();

    const int c4 = t * 4;
    f32x4 acc[8];
#pragma unroll
    for (int r = 0; r < 8; ++r) acc[r] = f32x4{0.f, 0.f, 0.f, 0.f};
    for (int k = 0; k < 512; ++k) {
      f32x4 w = *reinterpret_cast<const f32x4*>(Wpe + (size_t)k * 1024 + c4);
#pragma unroll
      for (int r = 0; r < 8; ++r) acc[r] += sec[r * 512 + k] * w;
    }
    f32x4 bb = *reinterpret_cast<const f32x4*>(bpe + c4);
#pragma unroll
    for (int r = 0; r < 8; ++r) {
      f32x4 o = acc[r] + bb;
      f16x4 h;
#pragma unroll
      for (int i = 0; i < 4; ++i) h[i] = (_Float16)(o[i] > 0.f ? o[i] : 0.f);
      *reinterpret_cast<f16x4*>(er + (size_t)(rb + r) * 1024 + c4) = h;
    }
  }
}

// ---------------------------------------------------------------------------
// staging: NI chunks of 8KB; linear LDS dest, source pre-swizzled. (verified)
// ---------------------------------------------------------------------------
template<int NI>
__device__ __forceinline__ void stage_tile(const _Float16* __restrict__ src, int ldk,
                                           int rcBase, int kt, _Float16* sbuf, int tid)
{
#pragma unroll
  for (int j = 0; j < NI; ++j) {
    int o  = j * 8192 + tid * 16;          // linear LDS byte offset
    int op = swz(o);                        // logical (row,kbyte) it must hold
    int r  = op >> 7;
    int kh = (op & 127) >> 1;
    gload_lds16(src + (size_t)(rcBase + r) * ldk + kt + kh,
                sbuf + (o - (tid & 63) * 16) / 2);   // wave-uniform base
  }
}

// ---------------------------------------------------------------------------
// main fused dual-GEMM: out = (Acat@Wc^T + bc) * (Auf@Wu^T + bu)
// BM=256 BN=128 BK=64, 512 thr = 8 waves (4x2), wave tile 64x64.
// r9 skeleton (3-buffer, depth-2, vmcnt(6), ONE barrier/tile, XCD-col map,
// unfenced interior). NEW: cat-GEMM A is gathered ON THE FLY from edge_rep
// via per-lane gload_lds source addresses (A_cat[r][c] =
// edge_rep[pidx[r][c<512?0:1]][c]) -- no Acat materialization.
// Unified 48-tile K loop: tiles 0..31 = union (K=2048), 32..47 = cat (K=1024).
// ---------------------------------------------------------------------------
#define NT  48
#define NTU 32

__global__ __launch_bounds__(512, 2) void k_main(
    const _Float16* __restrict__ er,  const int* __restrict__ pidx,
    const _Float16* __restrict__ Auf,
    const _Float16* __restrict__ Btc, const _Float16* __restrict__ Btu,
    const float* __restrict__ bcat, const float* __restrict__ bup,
    float* __restrict__ out)
{
  extern __shared__ char smem[];                    // 144 KiB dynamic
  _Float16* bufA[3] = { reinterpret_cast<_Float16*>(smem),
                        reinterpret_cast<_Float16*>(smem + 32768),
                        reinterpret_cast<_Float16*>(smem + 65536) };
  _Float16* bufB[3] = { reinterpret_cast<_Float16*>(smem + 98304),
                        reinterpret_cast<_Float16*>(smem + 98304 + 16384),
                        reinterpret_cast<_Float16*>(smem + 98304 + 32768) };

  const int tid  = threadIdx.x;
  const int lane = tid & 63, lr = lane & 15, lg = lane >> 4;
  const int wid  = tid >> 6, wr = wid >> 1, wc = wid & 1;      // 4x2 wave grid

  // XCD column-ownership mapping: xcd = bid&7 owns cols [xcd*512, xcd*512+512)
  const int bid = blockIdx.x;
  const int xcd = bid & 7;
  const int seq = bid >> 3;                 // 0..1023
  const int rowBase = (seq >> 2) * 256;
  const int colBase = (xcd * 4 + (seq & 3)) * 128;

  // per-thread swizzled LDS read offsets
  const int key  = (lr & 7) << 4;
  int kb[2];
  kb[0] = (lg * 16) ^ key;
  kb[1] = (64 + lg * 16) ^ key;
  const int aoff = (wr * 64 + lr) * 128;
  const int boff = (wc * 64 + lr) * 128;

  // fused-gather source pointers for the cat GEMM's A staging:
  // chunk j of an A-stage covers fixed (row r_j, k-offset kh_j) per thread.
  const _Float16* catH[4];
  const _Float16* catT[4];
#pragma unroll
  for (int j = 0; j < 4; ++j) {
    int o  = j * 8192 + tid * 16;
    int op = swz(o);
    int r  = op >> 7;                    // 0..255
    int kh = (op & 127) >> 1;            // 0..63 (f16 elems)
    int gr = rowBase + r;
    catH[j] = er + (size_t)pidx[2 * gr]     * 1024 + kh;
    catT[j] = er + (size_t)pidx[2 * gr + 1] * 1024 + kh;
  }

  f16x8 af[4][2], bf[4][2];
  f32x4 accU[4][4] = {};
  f32x4 accP[4][4] = {};

  // rotating buffer pointers: cur = tile t, nxt = t+1, fre = stage target (t+2)
  _Float16 *Ac = bufA[0], *An = bufA[1], *Af = bufA[2];
  _Float16 *Bc = bufB[0], *Bn = bufB[1], *Bf = bufB[2];

  // prologue: stage tiles 0 and 1 (union)
  stage_tile<4>(Auf, 2048, rowBase, 0,  Ac, tid);
  stage_tile<2>(Btu, 2048, colBase, 0,  Bc, tid);
  stage_tile<4>(Auf, 2048, rowBase, 64, An, tid);
  stage_tile<2>(Btu, 2048, colBase, 64, Bn, tid);

#define TILE_BODY(ACC)                                                          \
  do {                                                                          \
    if (t < NT - 1) asm volatile("s_waitcnt vmcnt(6)" ::: "memory");            \
    else            asm volatile("s_waitcnt vmcnt(0)" ::: "memory");            \
    __builtin_amdgcn_s_barrier();                                               \
    if (t + 2 < NT) {                                                           \
      const int tt = t + 2;                                                     \
      if (tt < NTU) { stage_tile<4>(Auf,  2048, rowBase, tt * 64, Af, tid);     \
                      stage_tile<2>(Btu,  2048, colBase, tt * 64, Bf, tid); }   \
      else {                                                                    \
        const int ktp  = (tt - NTU) * 64;                                       \
        const bool tail = ktp >= 512;                                           \
        char* AfB = reinterpret_cast<char*>(Af);                                \
        _Pragma("unroll") for (int j = 0; j < 4; ++j) {                         \
          int o = j * 8192 + tid * 16;                                          \
          const _Float16* src = (tail ? catT[j] : catH[j]) + ktp;               \
          gload_lds16(src, AfB + (o - lane * 16));                              \
        }                                                                       \
        stage_tile<2>(Btc, 1024, colBase, ktp, Bf, tid);                        \
      }                                                                         \
    }                                                                           \
    const char* aB = reinterpret_cast<const char*>(Ac) + aoff;                  \
    const char* bB = reinterpret_cast<const char*>(Bc) + boff;                  \
    /* unfenced: compiler interleaves read issue, addr VALU and MFMA */         \
    _Pragma("unroll") for (int m = 0; m < 4; ++m)                               \
      _Pragma("unroll") for (int ks = 0; ks < 2; ++ks)                          \
        af[m][ks] = *reinterpret_cast<const f16x8*>(aB + m * 2048 + kb[ks]);    \
    _Pragma("unroll") for (int n = 0; n < 4; ++n)                               \
      _Pragma("unroll") for (int ks = 0; ks < 2; ++ks)                          \
        bf[n][ks] = *reinterpret_cast<const f16x8*>(bB + n * 2048 + kb[ks]);    \
    _Pragma("unroll") for (int m = 0; m < 4; ++m)                               \
      _Pragma("unroll") for (int n = 0; n < 4; ++n)                             \
        _Pragma("unroll") for (int ks = 0; ks < 2; ++ks)                        \
          ACC[m][n] = __builtin_amdgcn_mfma_f32_16x16x32_f16(af[m][ks], bf[n][ks], ACC[m][n], 0, 0, 0); \
    _Float16* tA = Ac; Ac = An; An = Af; Af = tA;                               \
    _Float16* tB = Bc; Bc = Bn; Bn = Bf; Bf = tB;                               \
  } while (0)

  for (int t = 0; t < NTU; ++t) TILE_BODY(accU);
  for (int t = NTU; t < NT; ++t) TILE_BODY(accP);
#undef TILE_BODY

  // ---------------- epilogue ----------------
#pragma unroll
  for (int n = 0; n < 4; ++n) {
    const int col = colBase + wc * 64 + n * 16 + lr;
    const float bc = bcat[col], bu = bup[col];
#pragma unroll
    for (int m = 0; m < 4; ++m) {
      const int row0 = rowBase + wr * 64 + m * 16 + lg * 4;
#pragma unroll
      for (int i = 0; i < 4; ++i)
        out[(size_t)(row0 + i) * 4096 + col] =
            (accP[m][n][i] + bc) * (accU[m][n][i] + bu);
    }
  }
}

// ---------------------------------------------------------------------------
extern "C" void kernel_launch(void* const* d_in, const int* in_sizes, int n_in,
                              void* d_out, int out_size, void* d_ws, size_t ws_size,
                              hipStream_t stream)
{
  const float* edge_ctx = (const float*)d_in[0];
  const int*   pair_idx = (const int*)d_in[1];
  const float* uf       = (const float*)d_in[2];
  const float* Wpe      = (const float*)d_in[3];
  const float* bpe      = (const float*)d_in[4];
  const float* Wpc      = (const float*)d_in[5];
  const float* bpc      = (const float*)d_in[6];
  const float* Wup      = (const float*)d_in[7];
  const float* bup      = (const float*)d_in[8];
  float* out = (float*)d_out;

  char* ws = (char*)d_ws;
  _Float16* edge_rep = (_Float16*)ws;                                // 2.6 MB region
  _Float16* Auf  = (_Float16*)(ws + 5242880);                        // 256 MB
  _Float16* Btc  = (_Float16*)(ws + 5242880 + 268435456);            //   8 MB
  _Float16* Btu  = (_Float16*)(ws + 5242880 + 268435456 + 8388608);  //  16 MB

  (void)hipFuncSetAttribute((const void*)k_main,
                            hipFuncAttributeMaxDynamicSharedMemorySize, 147456);

  // merged prepass: cvt (65536) + wt_c (1024) + wt_u (2048) + edge (160)
  k_pre<<<68768, 256, 0, stream>>>(uf, Auf, Wpc, Btc, Wup, Btu,
                                   edge_ctx, Wpe, bpe, edge_rep);
  k_main<<<8192, 512, 147456, stream>>>(edge_rep, pair_idx, Auf, Btc, Btu,
                                        bpc, bup, out);
}